// Round 22
// baseline (55.429 us; speedup 1.0000x reference)
//
#include <hip/hip_runtime.h>
#include <hip/hip_bf16.h>
#include <math.h>

#define BS 8192
#define D 128
#define NROWS 16384               // 2*BS
#define NJOBS_N 512               // noise jobs: 32 mb x 16 nb (256r x 512c)
#define NJOBS_F 528               // f.f^T upper-triangle tiles (256 x 256)
#define NJOBS (NJOBS_N + NJOBS_F) // 1040

typedef int i32x4 __attribute__((ext_vector_type(4)));
typedef int i32x8 __attribute__((ext_vector_type(8)));
typedef float f32x4 __attribute__((ext_vector_type(4)));

#define LN2F 0.6931471805599453f
// store scale: elements written as x * 2^4 * sqrt(log2e) / ||row||; HW E8M0
// scale 2^-4 on A and B restores acc = sim * log2e exactly (powers of 2).
// For fp4(e2m1): max stored |x| ~ 0.31*19.2 = 5.95 <= 6 (fp4 max) — fits.
#define STORE_SCALE 19.217958569050494f   // 16 * 1.2011224087864498
#define E8M0_M4 123                       // 2^(123-127) = 2^-4
#define FMT_FP4 4                         // cbsz/blgp format code for e2m1

#if __has_builtin(__builtin_amdgcn_exp2f)
#define EXP2F(x) __builtin_amdgcn_exp2f(x)
#else
#define EXP2F(x) exp2f(x)
#endif

// Layout of catF (fp4, "16-row-group tiled"): cell = 16 rows x K=128 fp4 =
// 1024 B contiguous. Byte addr of (row, k): (row>>4)*1024 + (k>>5)*256 +
// (row&15)*16 + (k&31)/2 ; even k = LOW nibble, odd k = HIGH nibble.

// Kernel 1: row norms + scaled fp4(e2m1) conversion into catF.
// e2m1 code by 7-threshold count: codes 0..7 = {0,.5,1,1.5,2,3,4,6}.
// Also re-zeroes the finalize completion counter (graph-replay safe).
__global__ __launch_bounds__(256) void nrm_cvt(const float* __restrict__ f,
                                               const float* __restrict__ noise,
                                               char* __restrict__ catF,
                                               unsigned int* __restrict__ cnt) {
  if (blockIdx.x == 0 && threadIdx.x == 0) cnt[0] = 0;
  const int lane = threadIdx.x & 63;
  const int wv = threadIdx.x >> 6;
  const int row = blockIdx.x * 4 + wv;
  const float* src = (row < BS) ? (noise + (size_t)row * D) : (f + (size_t)(row - BS) * D);
  float2 v = ((const float2*)src)[lane];   // k = 2*lane, 2*lane+1 (same byte)
  float ss = v.x * v.x + v.y * v.y;
#pragma unroll
  for (int m = 1; m <= 32; m <<= 1) ss += __shfl_xor(ss, m, 64);
  const float s = STORE_SCALE / sqrtf(ss);
  auto q4 = [](float x) {
    const float av = fabsf(x);
    int c = (av > 0.25f) + (av > 0.75f) + (av > 1.25f) + (av > 1.75f) +
            (av > 2.5f) + (av > 3.5f) + (av > 5.0f);
    return c | ((x < 0.f) ? 8 : 0);
  };
  const int b = q4(v.x * s) | (q4(v.y * s) << 4);  // even k low nibble
  const int b1 = __shfl_down(b, 1, 64);
  const int b2 = __shfl_down(b, 2, 64);
  const int b3 = __shfl_down(b, 3, 64);
  if ((lane & 3) == 0) {
    const unsigned word = (unsigned)b | ((unsigned)b1 << 8) |
                          ((unsigned)b2 << 16) | ((unsigned)b3 << 24);
    char* dst = catF + ((size_t)(row >> 4) << 10) + ((lane >> 4) << 8) +
                ((row & 15) << 4) + (lane & 15);
    *(unsigned*)dst = word;
  }
}

__device__ __forceinline__ i32x8 mk8(i32x4 v) {
  i32x8 r = {v[0], v[1], v[2], v[3], 0, 0, 0, 0};
  return r;
}

// Kernel 2: fused GEMM + exp2 + row/col-sum, MX-FP4 K=128, acc double-buffer,
// f.f^T TRIANGLE SYMMETRY v2 (square 256x256 tiles, lean bookkeeping):
//   jobs [0,512):   noise half, 256r x 512c — R21 path verbatim (pos diag).
//                   rowsums -> wsN[nb][row] (16 planes).
//   jobs [512,1040): f.f^T tile (g,h), h >= g, 256x256. Off-diag (h>g) tiles
//                   are entirely strictly-upper: full rowsum AND colsum (the
//                   colsum is, by symmetry, the lower-half row contribution
//                   of the mirrored rows). Diag (h==g): single strict-upper
//                   mask (gcol > grow) serves both self-sim exclusion and
//                   lower-half elimination, for rowsum and colsum alike.
//                   rowsums -> rowF[h][row]; colsums -> colP[g][col]
//                   (unique writers, deterministic). Strictly-lower tiles
//                   (248 of 1024 elements-equivalents) are NEVER computed:
//                   -24.2% of exp+MFMA+loads — exp is the dominant measured
//                   term (R19 ablation: 13 of 26 us).
// Colsum path: per chunk 16 adds + 2 shfl + one 16-lane ds_write into a
// 4x256 LDS slab; combined across the block's 4 waves once per tile.
__global__ __launch_bounds__(256) void infonce_main(
    const char* __restrict__ catF,
    float* __restrict__ wsN, float* __restrict__ rowF,
    float* __restrict__ colP, float* __restrict__ ws_pos) {
  __shared__ float cls[4][256];
  const int tid = threadIdx.x;
  const int lane = tid & 63;
  const int w = tid >> 6;
  const int l15 = lane & 15, l4 = lane >> 4;
  const int jid = blockIdx.x;
  const f32x4 z = {0.f, 0.f, 0.f, 0.f};

  f32x4 rs[4];
#pragma unroll
  for (int rf = 0; rf < 4; rf++) rs[rf] = z;
  const int lbase = l4 * 256 + l15 * 16;

  if (jid < NJOBS_N) {
    // ---------------- noise half (R21 verbatim, 32 chunks) ----------------
    const int mb = jid >> 4, nb = jid & 15;
    const int growbase = mb * 256 + w * 64;  // f-row (global f index)
    const int col0 = nb * 512;               // cat col (noise half)

    i32x8 a[4];
    {
      const char* ab = catF + ((size_t)((BS + growbase) >> 4) << 10) + lbase;
#pragma unroll
      for (int rf = 0; rf < 4; rf++) a[rf] = mk8(*(const i32x4*)(ab + rf * 1024));
    }
    const char* bl = catF + ((size_t)(col0 >> 4) << 10) + lbase;
    auto ld = [&](int c) { return mk8(*(const i32x4*)(bl + (size_t)c * 1024)); };
    auto domfma = [&](f32x4* acc, const i32x8& b) {
#pragma unroll
      for (int rf = 0; rf < 4; rf++)
        acc[rf] = __builtin_amdgcn_mfma_scale_f32_16x16x128_f8f6f4(
            a[rf], b, z, FMT_FP4, FMT_FP4, 0, E8M0_M4, 0, E8M0_M4);
    };
    auto epi = [&](const f32x4* acc, int c) {
      const int c0 = col0 + c * 16;
      if ((c0 & ~63) != growbase) {
#pragma unroll
        for (int rf = 0; rf < 4; rf++) {
          f32x4 e;
#pragma unroll
          for (int r = 0; r < 4; r++) e[r] = EXP2F(acc[rf][r]);
          rs[rf] += e;
        }
      } else {
#pragma unroll
        for (int rf = 0; rf < 4; rf++)
#pragma unroll
          for (int r = 0; r < 4; r++) {
            const int grow = growbase + rf * 16 + l4 * 4 + r;
            const int gcol = c0 + l15;
            const float v = acc[rf][r];
            const bool ex = (gcol == grow);
            if (ex) ws_pos[grow] = v;  // sim_pos * log2e
            rs[rf][r] += ex ? 0.f : EXP2F(v);
          }
      }
    };

    i32x8 bb[4];
    bb[0] = ld(0);
    bb[1] = ld(1);
    f32x4 accA[4], accB[4];
    domfma(accA, bb[0]);
    bb[2] = ld(2);
    domfma(accB, bb[1]);
    bb[3] = ld(3);
#pragma unroll
    for (int ph = 0; ph < 15; ++ph) {
      const int c = 2 * ph;
      __builtin_amdgcn_sched_barrier(0);
      epi(accA, c);
      if (c + 4 < 32) bb[(c + 4) & 3] = ld(c + 4);
      domfma(accA, bb[(c + 2) & 3]);
      __builtin_amdgcn_sched_barrier(0);
      epi(accB, c + 1);
      if (c + 5 < 32) bb[(c + 5) & 3] = ld(c + 5);
      domfma(accB, bb[(c + 3) & 3]);
    }
    __builtin_amdgcn_sched_barrier(0);
    epi(accA, 30);
    epi(accB, 31);

    float rowsum[16];
#pragma unroll
    for (int rf = 0; rf < 4; rf++)
#pragma unroll
      for (int r = 0; r < 4; r++) {
        float v = rs[rf][r];
        v += __shfl_xor(v, 1, 64);
        v += __shfl_xor(v, 2, 64);
        v += __shfl_xor(v, 4, 64);
        v += __shfl_xor(v, 8, 64);
        rowsum[rf * 4 + r] = v;
      }
    if (l15 == 0) {
      float* dst = wsN + (size_t)nb * BS + growbase;
#pragma unroll
      for (int rf = 0; rf < 4; rf++)
#pragma unroll
        for (int r = 0; r < 4; r++) dst[rf * 16 + l4 * 4 + r] = rowsum[rf * 4 + r];
    }
  } else {
    // ---------------- f.f^T upper-triangle tile (g,h), 16 chunks ----------
    const int t = jid - NJOBS_N;
    // invert cum(g) = g*(65-g)/2 over g in [0,32)
    int g = (int)((65.0f - sqrtf(4225.0f - 8.0f * (float)t)) * 0.5f);
    while ((g + 1) * (65 - (g + 1)) / 2 <= t) ++g;
    while (g * (65 - g) / 2 > t) --g;
    const int h = g + (t - g * (65 - g) / 2);
    const bool diag = (h == g);
    const int growbase = g * 256 + w * 64;   // f-row (f-local)
    const int colf0 = h * 256;               // f-col (f-local)

    i32x8 a[4];
    {
      const char* ab = catF + ((size_t)((BS + growbase) >> 4) << 10) + lbase;
#pragma unroll
      for (int rf = 0; rf < 4; rf++) a[rf] = mk8(*(const i32x4*)(ab + rf * 1024));
    }
    const char* bl = catF + ((size_t)((BS + colf0) >> 4) << 10) + lbase;
    auto ld = [&](int c) { return mk8(*(const i32x4*)(bl + (size_t)c * 1024)); };
    auto domfma = [&](f32x4* acc, const i32x8& b) {
#pragma unroll
      for (int rf = 0; rf < 4; rf++)
        acc[rf] = __builtin_amdgcn_mfma_scale_f32_16x16x128_f8f6f4(
            a[rf], b, z, FMT_FP4, FMT_FP4, 0, E8M0_M4, 0, E8M0_M4);
    };
    auto epi = [&](const f32x4* acc, int c) {
      float csum = 0.f;
      if (!diag) {
#pragma unroll
        for (int rf = 0; rf < 4; rf++)
#pragma unroll
          for (int r = 0; r < 4; r++) {
            const float e = EXP2F(acc[rf][r]);
            rs[rf][r] += e;
            csum += e;
          }
      } else {
        const int gcol = colf0 + c * 16 + l15;
#pragma unroll
        for (int rf = 0; rf < 4; rf++)
#pragma unroll
          for (int r = 0; r < 4; r++) {
            const int grow = growbase + rf * 16 + l4 * 4 + r;
            const float e = (gcol > grow) ? EXP2F(acc[rf][r]) : 0.f;
            rs[rf][r] += e;
            csum += e;
          }
      }
      csum += __shfl_xor(csum, 16, 64);
      csum += __shfl_xor(csum, 32, 64);
      if (l4 == 0) cls[w][c * 16 + l15] = csum;
    };

    i32x8 bb[4];
    bb[0] = ld(0);
    bb[1] = ld(1);
    f32x4 accA[4], accB[4];
    domfma(accA, bb[0]);
    bb[2] = ld(2);
    domfma(accB, bb[1]);
    bb[3] = ld(3);
#pragma unroll
    for (int ph = 0; ph < 7; ++ph) {
      const int c = 2 * ph;
      __builtin_amdgcn_sched_barrier(0);
      epi(accA, c);
      if (c + 4 < 16) bb[(c + 4) & 3] = ld(c + 4);
      domfma(accA, bb[(c + 2) & 3]);
      __builtin_amdgcn_sched_barrier(0);
      epi(accB, c + 1);
      if (c + 5 < 16) bb[(c + 5) & 3] = ld(c + 5);
      domfma(accB, bb[(c + 3) & 3]);
    }
    __builtin_amdgcn_sched_barrier(0);
    epi(accA, 14);
    epi(accB, 15);

    float rowsum[16];
#pragma unroll
    for (int rf = 0; rf < 4; rf++)
#pragma unroll
      for (int r = 0; r < 4; r++) {
        float v = rs[rf][r];
        v += __shfl_xor(v, 1, 64);
        v += __shfl_xor(v, 2, 64);
        v += __shfl_xor(v, 4, 64);
        v += __shfl_xor(v, 8, 64);
        rowsum[rf * 4 + r] = v;
      }
    if (l15 == 0) {
      float* dst = rowF + (size_t)h * BS + growbase;
#pragma unroll
      for (int rf = 0; rf < 4; rf++)
#pragma unroll
        for (int r = 0; r < 4; r++) dst[rf * 16 + l4 * 4 + r] = rowsum[rf * 4 + r];
    }
    // combine the 4 waves' colsums, store plane g (cols of group h)
    __syncthreads();
    colP[(size_t)g * BS + colf0 + tid] =
        cls[0][tid] + cls[1][tid] + cls[2][tid] + cls[3][tid];
  }
}

// Kernel 3: per-row loss + mean, single kernel (last-block-done tail).
// Row r (group gr=r>>8): neg = 16 noise planes + rowF[h>=gr] + colP[g<=gr].
__global__ __launch_bounds__(256) void finalize(const float* __restrict__ wsN,
                                                const float* __restrict__ rowF,
                                                const float* __restrict__ colP,
                                                const float* __restrict__ ws_pos,
                                                float* __restrict__ partial,
                                                unsigned int* __restrict__ cnt,
                                                float* __restrict__ out) {
  __shared__ float red[4];
  __shared__ int flag;
  const int tid = threadIdx.x;
  const int lane = tid & 63;
  const int w = tid >> 6;
  const int row = blockIdx.x * 256 + tid;
  const int gr = row >> 8;
  float neg = 0.f;
#pragma unroll
  for (int p = 0; p < 16; p++) neg += wsN[(size_t)p * BS + row];
  for (int h = gr; h < 32; h++) neg += rowF[(size_t)h * BS + row];
  for (int g = 0; g <= gr; g++) neg += colP[(size_t)g * BS + row];
  // loss = log(neg_sum + eps) - sim_pos ; sim_pos = (sim*log2e)*ln2
  float local = logf(neg + 1e-6f) - ws_pos[row] * LN2F;
#pragma unroll
  for (int m = 1; m <= 32; m <<= 1) local += __shfl_xor(local, m, 64);
  if (lane == 0) red[w] = local;
  __syncthreads();
  if (tid == 0) {
    partial[blockIdx.x] = red[0] + red[1] + red[2] + red[3];
    __threadfence();  // release: partial visible before the bump
    flag = (atomicAdd(cnt, 1u) == (unsigned)(BS / 256 - 1));
  }
  __syncthreads();
  if (!flag) return;
  __threadfence();    // acquire: see all blocks' partials
  if (tid < 64) {
    float v = (tid < 32) ? partial[tid] : 0.f;
#pragma unroll
    for (int m = 1; m <= 32; m <<= 1) v += __shfl_xor(v, m, 64);
    if (tid == 0) out[0] = v * (1.f / BS);
  }
}

extern "C" void kernel_launch(void* const* d_in, const int* in_sizes, int n_in,
                              void* d_out, int out_size, void* d_ws, size_t ws_size,
                              hipStream_t stream) {
  const float* f = (const float*)d_in[0];
  const float* noise = (const float*)d_in[1];
  char* ws = (char*)d_ws;
  char* catF = ws;                                  // 1 MiB (fp4 tiled)
  float* ws_pos = (float*)(ws + (size_t)NROWS * 64);// 32 KiB
  float* wsN = ws_pos + BS;                         // 512 KiB (16 planes)
  float* rowF = wsN + (size_t)16 * BS;              // 1 MiB (32 planes)
  float* colP = rowF + (size_t)32 * BS;             // 1 MiB (32 planes)
  float* partial = colP + (size_t)32 * BS;          // 128 B
  unsigned int* cnt = (unsigned int*)(partial + 32);

  nrm_cvt<<<NROWS / 4, 256, 0, stream>>>(f, noise, catF, cnt);
  infonce_main<<<NJOBS, 256, 0, stream>>>(catF, wsN, rowF, colP, ws_pos);
  finalize<<<BS / 256, 256, 0, stream>>>(wsN, rowF, colP, ws_pos, partial, cnt,
                                         (float*)d_out);
}

// Round 23
// 36.106 us; speedup vs baseline: 1.5352x; 1.5352x over previous
//
#include <hip/hip_runtime.h>
#include <hip/hip_bf16.h>
#include <math.h>

#define BS 8192
#define D 128
#define NROWS 16384               // 2*BS
#define COLS_PER_BLOCK 512
#define NCHUNK (COLS_PER_BLOCK / 16)      // 32 col-chunks of 16
#define NSPLIT (NROWS / COLS_PER_BLOCK)   // 32 col-splits
#define NPART NSPLIT                      // 32 partial buffers

typedef int i32x4 __attribute__((ext_vector_type(4)));
typedef int i32x8 __attribute__((ext_vector_type(8)));
typedef float f32x4 __attribute__((ext_vector_type(4)));

#define LN2F 0.6931471805599453f
// store scale: elements written as x * 2^4 * sqrt(log2e) / ||row||; HW E8M0
// scale 2^-4 on A and B restores acc = sim * log2e exactly (powers of 2).
// For fp4(e2m1): max stored |x| ~ 0.31*19.2 = 5.95 <= 6 (fp4 max) — fits.
#define STORE_SCALE 19.217958569050494f   // 16 * 1.2011224087864498
#define E8M0_M4 123                       // 2^(123-127) = 2^-4
#define FMT_FP4 4                         // cbsz/blgp format code for e2m1

#if __has_builtin(__builtin_amdgcn_exp2f)
#define EXP2F(x) __builtin_amdgcn_exp2f(x)
#else
#define EXP2F(x) exp2f(x)
#endif

// Layout of catF (fp4, "16-row-group tiled"): cell = 16 rows x K=128 fp4 =
// 1024 B contiguous. Byte addr of (row, k): (row>>4)*1024 + (k>>5)*256 +
// (row&15)*16 + (k&31)/2 ; even k = LOW nibble, odd k = HIGH nibble.
// An MFMA fragment (lanes: l15=row/col, l4=k-block-of-32) is lane 16B at
// l4*256 + l15*16 — the wave's 64x16B = the whole 1 KiB cell, coalesced.

// Kernel 1: row norms + scaled fp4(e2m1) conversion into catF.
// e2m1 code by 7-threshold count: codes 0..7 = {0,.5,1,1.5,2,3,4,6}.
// Also re-zeroes the finalize completion counter (graph-replay safe).
__global__ __launch_bounds__(256) void nrm_cvt(const float* __restrict__ f,
                                               const float* __restrict__ noise,
                                               char* __restrict__ catF,
                                               unsigned int* __restrict__ cnt) {
  if (blockIdx.x == 0 && threadIdx.x == 0) cnt[0] = 0;
  const int lane = threadIdx.x & 63;
  const int wv = threadIdx.x >> 6;
  const int row = blockIdx.x * 4 + wv;
  const float* src = (row < BS) ? (noise + (size_t)row * D) : (f + (size_t)(row - BS) * D);
  float2 v = ((const float2*)src)[lane];   // k = 2*lane, 2*lane+1 (same byte)
  float ss = v.x * v.x + v.y * v.y;
#pragma unroll
  for (int m = 1; m <= 32; m <<= 1) ss += __shfl_xor(ss, m, 64);
  const float s = STORE_SCALE / sqrtf(ss);
  auto q4 = [](float x) {
    const float av = fabsf(x);
    int c = (av > 0.25f) + (av > 0.75f) + (av > 1.25f) + (av > 1.75f) +
            (av > 2.5f) + (av > 3.5f) + (av > 5.0f);
    return c | ((x < 0.f) ? 8 : 0);
  };
  const int b = q4(v.x * s) | (q4(v.y * s) << 4);  // even k low nibble
  const int b1 = __shfl_down(b, 1, 64);
  const int b2 = __shfl_down(b, 2, 64);
  const int b3 = __shfl_down(b, 3, 64);
  if ((lane & 3) == 0) {
    const unsigned word = (unsigned)b | ((unsigned)b1 << 8) |
                          ((unsigned)b2 << 16) | ((unsigned)b3 << 24);
    char* dst = catF + ((size_t)(row >> 4) << 10) + ((lane >> 4) << 8) +
                ((row & 15) << 4) + (lane & 15);
    *(unsigned*)dst = word;
  }
}

__device__ __forceinline__ i32x8 mk8(i32x4 v) {
  i32x8 r = {v[0], v[1], v[2], v[3], 0, 0, 0, 0};
  return r;
}

// Kernel 2 (R21 verbatim — best measured, 36.1 us total): fused GEMM + exp2 +
// row-sum, MX-FP4 K=128, acc double-buffer. Measured model (R19 ablation):
// main = floor(8us: MFMA+loads+scaffold) + exp(13us, trans-pipe throughput
// floor for 134M v_exp_f32) + adds(5us), additive per wave. Work-removal is
// the only lever that has moved this wall (fp8 -12us, fp4 -4.2us); all
// scheduling levers null; triangle symmetry refuted twice (R12, R22).
__global__ __launch_bounds__(256) void infonce_main(
    const char* __restrict__ catF,
    float* __restrict__ ws_neg, float* __restrict__ ws_pos) {
  const int tid = threadIdx.x;
  const int lane = tid & 63;
  const int w = tid >> 6;
  const int l15 = lane & 15, l4 = lane >> 4;
  const int nb = blockIdx.x, mb = blockIdx.y;
  const int growbase = mb * 256 + w * 64;
  const int col0 = nb * COLS_PER_BLOCK;
  const int lbase = l4 * 256 + l15 * 16;

  // A fragments: 64 f-rows x K=128 fp4 (data in low 4 regs of each operand)
  i32x8 a[4];
  {
    const char* ab = catF + ((size_t)((BS + growbase) >> 4) << 10) + lbase;
#pragma unroll
    for (int rf = 0; rf < 4; rf++) a[rf] = mk8(*(const i32x4*)(ab + rf * 1024));
  }

  f32x4 rs[4];
  const f32x4 z = {0.f, 0.f, 0.f, 0.f};
#pragma unroll
  for (int rf = 0; rf < 4; rf++) rs[rf] = z;

  const char* bl = catF + ((size_t)(col0 >> 4) << 10) + lbase;

  auto ld = [&](int c) { return mk8(*(const i32x4*)(bl + (size_t)c * 1024)); };

  auto domfma = [&](f32x4* acc, const i32x8& b) {
#pragma unroll
    for (int rf = 0; rf < 4; rf++)
      acc[rf] = __builtin_amdgcn_mfma_scale_f32_16x16x128_f8f6f4(
          a[rf], b, z, FMT_FP4, FMT_FP4, 0, E8M0_M4, 0, E8M0_M4);
  };

  auto epi = [&](const f32x4* acc, int c) {
    const int c0 = col0 + c * 16;
    const bool dPos = ((c0 & ~63) == growbase);          // cols == f-row ids
    const bool dSelf = (((c0 - BS) & ~63) == growbase);  // cols == i+bs
    if (!dPos && !dSelf) {
#pragma unroll
      for (int rf = 0; rf < 4; rf++) {
        f32x4 e;
#pragma unroll
        for (int r = 0; r < 4; r++) e[r] = EXP2F(acc[rf][r]);
        rs[rf] += e;
      }
    } else {
#pragma unroll
      for (int rf = 0; rf < 4; rf++)
#pragma unroll
        for (int r = 0; r < 4; r++) {
          const int grow = growbase + rf * 16 + l4 * 4 + r;
          const int gcol = c0 + l15;
          const float v = acc[rf][r];
          const bool ex = dPos ? (gcol == grow) : (gcol == grow + BS);
          if (dPos && gcol == grow) ws_pos[grow] = v;  // sim_pos * log2e
          rs[rf][r] += ex ? 0.f : EXP2F(v);
        }
    }
  };

  // 4-slot B ring, loads 2 chunks ahead of their MFMA.
  i32x8 bb[4];
  bb[0] = ld(0);
  bb[1] = ld(1);

  f32x4 accA[4], accB[4];
  domfma(accA, bb[0]);   // chunk 0
  bb[2] = ld(2);
  domfma(accB, bb[1]);   // chunk 1
  bb[3] = ld(3);

#pragma unroll
  for (int ph = 0; ph < 15; ++ph) {
    const int c = 2 * ph;  // accA=chunk c (pending epi), accB=chunk c+1
    __builtin_amdgcn_sched_barrier(0);
    epi(accA, c);                          // covers accB's MFMA in flight
    if (c + 4 < NCHUNK) bb[(c + 4) & 3] = ld(c + 4);
    domfma(accA, bb[(c + 2) & 3]);         // chunk c+2
    __builtin_amdgcn_sched_barrier(0);
    epi(accB, c + 1);                      // covers accA's MFMA in flight
    if (c + 5 < NCHUNK) bb[(c + 5) & 3] = ld(c + 5);
    domfma(accB, bb[(c + 3) & 3]);         // chunk c+3
  }
  __builtin_amdgcn_sched_barrier(0);
  epi(accA, NCHUNK - 2);
  epi(accB, NCHUNK - 1);

  // reduce rowsums across the 16 lanes (l15) sharing each row
  float rowsum[16];
#pragma unroll
  for (int rf = 0; rf < 4; rf++)
#pragma unroll
    for (int r = 0; r < 4; r++) {
      float v = rs[rf][r];
      v += __shfl_xor(v, 1, 64);
      v += __shfl_xor(v, 2, 64);
      v += __shfl_xor(v, 4, 64);
      v += __shfl_xor(v, 8, 64);
      rowsum[rf * 4 + r] = v;
    }
  if (l15 == 0) {
    float* dst = ws_neg + (size_t)nb * BS + growbase;
#pragma unroll
    for (int rf = 0; rf < 4; rf++)
#pragma unroll
      for (int r = 0; r < 4; r++) dst[rf * 16 + l4 * 4 + r] = rowsum[rf * 4 + r];
  }
}

// Kernel 3: per-row loss + mean, single kernel (last-block-done tail).
__global__ __launch_bounds__(256) void finalize(const float* __restrict__ ws_neg,
                                                const float* __restrict__ ws_pos,
                                                float* __restrict__ partial,
                                                unsigned int* __restrict__ cnt,
                                                float* __restrict__ out) {
  __shared__ float red[4];
  __shared__ int flag;
  const int tid = threadIdx.x;
  const int lane = tid & 63;
  const int w = tid >> 6;
  const int row = blockIdx.x * 256 + tid;
  float neg = 0.f;
#pragma unroll
  for (int p = 0; p < NPART; p++) neg += ws_neg[(size_t)p * BS + row];
  // loss = log(neg_sum + eps) - sim_pos ; sim_pos = (sim*log2e)*ln2
  float local = logf(neg + 1e-6f) - ws_pos[row] * LN2F;
#pragma unroll
  for (int m = 1; m <= 32; m <<= 1) local += __shfl_xor(local, m, 64);
  if (lane == 0) red[w] = local;
  __syncthreads();
  if (tid == 0) {
    partial[blockIdx.x] = red[0] + red[1] + red[2] + red[3];
    __threadfence();  // release: partial visible before the bump
    flag = (atomicAdd(cnt, 1u) == (unsigned)(BS / 256 - 1));
  }
  __syncthreads();
  if (!flag) return;
  __threadfence();    // acquire: see all blocks' partials
  if (tid < 64) {
    float v = (tid < 32) ? partial[tid] : 0.f;
#pragma unroll
    for (int m = 1; m <= 32; m <<= 1) v += __shfl_xor(v, m, 64);
    if (tid == 0) out[0] = v * (1.f / BS);
  }
}

extern "C" void kernel_launch(void* const* d_in, const int* in_sizes, int n_in,
                              void* d_out, int out_size, void* d_ws, size_t ws_size,
                              hipStream_t stream) {
  const float* f = (const float*)d_in[0];
  const float* noise = (const float*)d_in[1];
  char* ws = (char*)d_ws;
  char* catF = ws;                                       // 1 MiB (fp4 tiled)
  float* ws_pos = (float*)(ws + (size_t)NROWS * 64);     // 32 KiB
  float* ws_neg = ws_pos + BS;                           // 1 MiB
  float* partial = ws_neg + (size_t)NPART * BS;          // 128 B
  unsigned int* cnt = (unsigned int*)(partial + 32);

  nrm_cvt<<<NROWS / 4, 256, 0, stream>>>(f, noise, catF, cnt);
  dim3 grid(NSPLIT, BS / 256);                           // 32 x 32 = 1024 blocks
  infonce_main<<<grid, 256, 0, stream>>>(catF, ws_neg, ws_pos);
  finalize<<<BS / 256, 256, 0, stream>>>(ws_neg, ws_pos, partial, cnt, (float*)d_out);
}